// Round 11
// baseline (407.780 us; speedup 1.0000x reference)
//
#include <hip/hip_runtime.h>

#define NFEAT 128
#define NCLS  10
#define NCP   16    // padded class count
#define BROW  512   // rows per bucket
#define BINC  4096  // items per binning chunk

static inline size_t alignup(size_t x) { return (x + 255) & ~size_t(255); }

// bf16 helpers (bit-level, RNE)
__device__ __forceinline__ ushort f2bf(float f) {
  uint x = __float_as_uint(f);
  return (ushort)((x + 0x7fffu + ((x >> 16) & 1u)) >> 16);
}
__device__ __forceinline__ float bf2f(ushort u) {
  return __uint_as_float(((uint)u) << 16);
}

typedef short bf16x8 __attribute__((ext_vector_type(8)));
typedef float f32x4 __attribute__((ext_vector_type(4)));

// ---------------- CSR build (bucketed, write-amplification-free) ----------------

__global__ __launch_bounds__(256) void bucket_hist(const int* __restrict__ dst,
                                                   int* __restrict__ bkt_cnt,
                                                   int e, int nbkt) {
  __shared__ int hist[256];
  for (int t = threadIdx.x; t < nbkt; t += 256) hist[t] = 0;
  __syncthreads();
  int i = blockIdx.x * 256 + threadIdx.x;
  int stride = gridDim.x * 256;
  for (; i < e; i += stride) atomicAdd(&hist[dst[i] >> 9], 1);
  __syncthreads();
  for (int t = threadIdx.x; t < nbkt; t += 256)
    if (hist[t]) atomicAdd(&bkt_cnt[t], hist[t]);
}

__global__ __launch_bounds__(256) void bkt_scan(const int* __restrict__ bkt_cnt,
                                                int* __restrict__ bkt_off,
                                                int* __restrict__ gfrontier,
                                                int n, int nbkt) {
  __shared__ int sbuf[256];
  const int t = threadIdx.x;
  int x = 0;
  if (t < nbkt) {
    int lo = t << 9;
    int nodes = n - lo; if (nodes > BROW) nodes = BROW;
    x = bkt_cnt[t] + nodes;
  }
  sbuf[t] = x;
  __syncthreads();
  for (int off = 1; off < 256; off <<= 1) {
    int v = (t >= off) ? sbuf[t - off] : 0;
    __syncthreads();
    sbuf[t] += v;
    __syncthreads();
  }
  if (t < nbkt) { bkt_off[t] = sbuf[t] - x; gfrontier[t] = sbuf[t] - x; }
  if (t == nbkt - 1) bkt_off[nbkt] = sbuf[t];
}

__global__ __launch_bounds__(256) void bin_items(const int* __restrict__ ei,
                                                 int nE, int total, int nbkt,
                                                 int* __restrict__ gfrontier,
                                                 int2* __restrict__ binned) {
  __shared__ int hist[256];
  __shared__ int loff[256];
  __shared__ int gbase[256];
  __shared__ int sbuf[256];
  __shared__ int2 st[BINC];
  const int t = threadIdx.x;
  const int chunk0 = blockIdx.x * BINC;
  for (int q = t; q < nbkt; q += 256) hist[q] = 0;
  __syncthreads();
  for (int j = t; j < BINC; j += 256) {
    int i = chunk0 + j;
    if (i < total) {
      int d = (i < nE) ? ei[nE + i] : (i - nE);
      atomicAdd(&hist[d >> 9], 1);
    }
  }
  __syncthreads();
  int x = (t < nbkt) ? hist[t] : 0;
  sbuf[t] = x;
  __syncthreads();
  for (int off = 1; off < 256; off <<= 1) {
    int v = (t >= off) ? sbuf[t - off] : 0;
    __syncthreads();
    sbuf[t] += v;
    __syncthreads();
  }
  loff[t] = sbuf[t] - x;
  gbase[t] = (t < nbkt && x > 0) ? atomicAdd(&gfrontier[t], x) : 0;
  __syncthreads();
  hist[t] = loff[t];
  __syncthreads();
  for (int j = t; j < BINC; j += 256) {
    int i = chunk0 + j;
    if (i < total) {
      int s, d;
      if (i < nE) { s = ei[i]; d = ei[nE + i]; }
      else        { s = i - nE; d = s; }
      int p = atomicAdd(&hist[d >> 9], 1);
      st[p] = make_int2(s, d);
    }
  }
  __syncthreads();
  int M = total - chunk0; if (M > BINC) M = BINC;
  for (int j = t; j < M; j += 256) {
    int2 it = st[j];
    int b = it.y >> 9;
    binned[gbase[b] + (j - loff[b])] = it;
  }
}

__global__ __launch_bounds__(512) void bucket_finalize(const int2* __restrict__ binned,
                                                       const int* __restrict__ bkt_off,
                                                       int* __restrict__ row_ptr,
                                                       float* __restrict__ dis,
                                                       int* __restrict__ ev,
                                                       int n, int nbkt) {
  __shared__ int hist[BROW];
  __shared__ int sbuf[BROW];
  __shared__ int pre[BROW];
  __shared__ int front[BROW];
  const int b = blockIdx.x;
  const int t = threadIdx.x;
  const int row0 = b << 9;
  const int beg = bkt_off[b], end = bkt_off[b + 1];
  hist[t] = 0; front[t] = 0;
  __syncthreads();
  for (int j = beg + t; j < end; j += BROW)
    atomicAdd(&hist[binned[j].y - row0], 1);
  __syncthreads();
  const int x = hist[t];
  const int v = row0 + t;
  if (v < n) dis[v] = rsqrtf((float)x);
  sbuf[t] = x;
  __syncthreads();
  for (int off = 1; off < BROW; off <<= 1) {
    int val = (t >= off) ? sbuf[t - off] : 0;
    __syncthreads();
    sbuf[t] += val;
    __syncthreads();
  }
  pre[t] = sbuf[t] - x;
  if (v < n) row_ptr[v] = beg + pre[t];
  if (b == nbkt - 1 && t == 0) row_ptr[n] = end;
  __syncthreads();
  for (int j = beg + t; j < end; j += BROW) {
    int2 it = binned[j];
    int dl = it.y - row0;
    int slot = atomicAdd(&front[dl], 1);
    ev[beg + pre[dl] + slot] = it.x;
  }
}

// ---------------- weight prep ----------------

// Wf[r][c](fp32) = (W3@Wl)[r][c]; bf[c] = (b3@Wl + bl)[c]
__global__ __launch_bounds__(256) void fold_weights(const float* __restrict__ W3,
                                                    const float* __restrict__ Wl,
                                                    const float* __restrict__ b3,
                                                    const float* __restrict__ bl,
                                                    float* __restrict__ Wf,
                                                    float* __restrict__ bf) {
  int t = blockIdx.x * blockDim.x + threadIdx.x;
  if (t < NFEAT * NCP) {
    int r = t >> 4, c = t & 15;
    float s = 0.f;
    if (c < NCLS) {
      for (int k = 0; k < NFEAT; ++k) s += W3[r * NFEAT + k] * Wl[k * NCLS + c];
    }
    Wf[t] = s;
  }
  if (t < NCP) {
    float s = 0.f;
    if (t < NCLS) {
      s = bl[t];
      for (int k = 0; k < NFEAT; ++k) s += b3[k] * Wl[k * NCLS + t];
    }
    bf[t] = s;
  }
}

// both weight transposes in one launch: Wt[n][k] (bf16) = W[k][n]
__global__ __launch_bounds__(256) void prep_w2(const float* __restrict__ W1,
                                               const float* __restrict__ W2,
                                               ushort* __restrict__ Wt1,
                                               ushort* __restrict__ Wt2) {
  int t = blockIdx.x * 256 + threadIdx.x;
  int u = t & 16383;
  int n = u >> 7, k = u & 127;
  if (t < 16384) Wt1[n * NFEAT + k] = f2bf(W1[k * NFEAT + n]);
  else           Wt2[n * NFEAT + k] = f2bf(W2[k * NFEAT + n]);
}

// ---- MFMA GEMM: sliced-out Cb = dis[r] * (A[r] @ W) ----
// Output: 2 planes of 64 feats: plane p, element (p*pstride + r*64 + f'), p = c>>2.
// BF16IN=false: A fp32 row-major. BF16IN=true: Ab bf16 row-major.

template<bool BF16IN>
__global__ __launch_bounds__(256) void gemm_mfma(const float* __restrict__ A,
                                                 const ushort* __restrict__ Ab,
                                                 const ushort* __restrict__ Wt,
                                                 const float* __restrict__ dis,
                                                 ushort* __restrict__ outS,
                                                 size_t pstride, int nrows) {
  __shared__ __align__(16) ushort Asm[64 * NFEAT];   // 16 KB
  const int tid = threadIdx.x;
  const int row0 = blockIdx.x * 64;
  {
    const int m = tid >> 2;
    const int kc = (tid & 3) * 32;
    const int gr = row0 + m;
    int4 u[4];
    if (BF16IN) {
      if (gr < nrows) {
        const ushort* p = Ab + (size_t)gr * NFEAT + kc;
        u[0] = *(const int4*)(p + 0);
        u[1] = *(const int4*)(p + 8);
        u[2] = *(const int4*)(p + 16);
        u[3] = *(const int4*)(p + 24);
      } else {
        u[0] = u[1] = u[2] = u[3] = make_int4(0, 0, 0, 0);
      }
    } else {
      float4 f[8];
      if (gr < nrows) {
        #pragma unroll
        for (int q = 0; q < 8; ++q)
          f[q] = *(const float4*)&A[(size_t)gr * NFEAT + kc + q * 4];
      } else {
        #pragma unroll
        for (int q = 0; q < 8; ++q) f[q] = make_float4(0.f, 0.f, 0.f, 0.f);
      }
      #pragma unroll
      for (int q = 0; q < 4; ++q) {
        union { ushort us[8]; int4 v; } pk;
        const float* fp = (const float*)&f[q * 2];
        #pragma unroll
        for (int j = 0; j < 8; ++j) pk.us[j] = f2bf(fp[j]);
        u[q] = pk.v;
      }
    }
    #pragma unroll
    for (int q = 0; q < 4; ++q) {
      int byte = (m * 256 + (kc + q * 8) * 2) ^ ((m & 7) << 4);
      *(int4*)((char*)Asm + byte) = u[q];
    }
  }
  __syncthreads();
  const int wave = tid >> 6;
  const int lane = tid & 63;
  const int m0 = wave * 16;
  bf16x8 afr[4];
  #pragma unroll
  for (int ks = 0; ks < 4; ++ks) {
    int m = m0 + (lane & 15);
    int kk = ks * 32 + (lane >> 4) * 8;
    int byte = (m * 256 + kk * 2) ^ ((m & 7) << 4);
    afr[ks] = *(const bf16x8*)((const char*)Asm + byte);
  }
  f32x4 acc[8];
  #pragma unroll
  for (int c = 0; c < 8; ++c) acc[c] = (f32x4){0.f, 0.f, 0.f, 0.f};
  #pragma unroll
  for (int c = 0; c < 8; ++c) {
    #pragma unroll
    for (int ks = 0; ks < 4; ++ks) {
      int n = c * 16 + (lane & 15);
      int kk = ks * 32 + (lane >> 4) * 8;
      bf16x8 bfr = *(const bf16x8*)&Wt[n * NFEAT + kk];
      acc[c] = __builtin_amdgcn_mfma_f32_16x16x32_bf16(afr[ks], bfr, acc[c], 0, 0, 0);
    }
  }
  const int gr_base = row0 + m0 + (lane >> 4) * 4;
  float dr[4];
  #pragma unroll
  for (int r = 0; r < 4; ++r)
    dr[r] = (gr_base + r < nrows) ? dis[gr_base + r] : 0.f;
  #pragma unroll
  for (int c = 0; c < 8; ++c) {
    ushort* plane = outS + (size_t)(c >> 2) * pstride;
    const int fcol = (c & 3) * 16 + (lane & 15);
    #pragma unroll
    for (int r = 0; r < 4; ++r) {
      int gr = gr_base + r;
      if (gr < nrows)
        plane[(size_t)gr * 64 + fcol] = f2bf(acc[c][r] * dr[r]);
    }
  }
}

// ------- sparse aggregation over sliced source -------
// slice = blockIdx&1 (rides round-robin block->XCD dispatch: even XCDs plane 0, odd plane 1).
// Per wave: 1 node, quarter-wave edge groups (16 lanes x ushort4 = 64 feats), stride 4,
// unroll 2 -> 8 gathers in flight (round-9 verified ILP). Output row-major bf16.

__global__ __launch_bounds__(256) void aggregate(const ushort* __restrict__ hbS,
                                                 const int* __restrict__ row_ptr,
                                                 const int* __restrict__ ev,
                                                 const float* __restrict__ dis,
                                                 const float* __restrict__ bias,
                                                 ushort* __restrict__ outb,
                                                 size_t pstride, int relu, int n) {
  const int slice = blockIdx.x & 1;
  const int wave = threadIdx.x >> 6;
  const int lane = threadIdx.x & 63;
  const int v = (blockIdx.x >> 1) * 4 + wave;
  if (v >= n) return;
  const int beg = row_ptr[v], end = row_ptr[v + 1];
  const int qg = lane >> 4;          // edge group 0..3
  const int hl = lane & 15;          // feature group within 64: feats hl*4 .. +3
  const ushort* plane = hbS + (size_t)slice * pstride;
  float4 acc = make_float4(0.f, 0.f, 0.f, 0.f);
  int e = beg + qg;
  for (; e + 4 < end; e += 8) {      // 2 edges per group per iter -> 8 gathers in flight
    int s0 = ev[e];
    int s1 = ev[e + 4];
    ushort4 q0 = *(const ushort4*)&plane[(size_t)s0 * 64 + hl * 4];
    ushort4 q1 = *(const ushort4*)&plane[(size_t)s1 * 64 + hl * 4];
    acc.x += bf2f(q0.x) + bf2f(q1.x);
    acc.y += bf2f(q0.y) + bf2f(q1.y);
    acc.z += bf2f(q0.z) + bf2f(q1.z);
    acc.w += bf2f(q0.w) + bf2f(q1.w);
  }
  for (; e < end; e += 4) {
    int s = ev[e];
    ushort4 q = *(const ushort4*)&plane[(size_t)s * 64 + hl * 4];
    acc.x += bf2f(q.x); acc.y += bf2f(q.y);
    acc.z += bf2f(q.z); acc.w += bf2f(q.w);
  }
  acc.x += __shfl_xor(acc.x, 16); acc.x += __shfl_xor(acc.x, 32);
  acc.y += __shfl_xor(acc.y, 16); acc.y += __shfl_xor(acc.y, 32);
  acc.z += __shfl_xor(acc.z, 16); acc.z += __shfl_xor(acc.z, 32);
  acc.w += __shfl_xor(acc.w, 16); acc.w += __shfl_xor(acc.w, 32);
  if (qg == 0) {
    float dv = dis[v];
    float4 b = *(const float4*)&bias[slice * 64 + hl * 4];
    acc.x = fmaf(acc.x, dv, b.x); acc.y = fmaf(acc.y, dv, b.y);
    acc.z = fmaf(acc.z, dv, b.z); acc.w = fmaf(acc.w, dv, b.w);
    if (relu) {
      acc.x = fmaxf(acc.x, 0.f); acc.y = fmaxf(acc.y, 0.f);
      acc.z = fmaxf(acc.z, 0.f); acc.w = fmaxf(acc.w, 0.f);
    }
    union { ushort us[4]; uint2 q2; } pk;
    pk.us[0] = f2bf(acc.x); pk.us[1] = f2bf(acc.y);
    pk.us[2] = f2bf(acc.z); pk.us[3] = f2bf(acc.w);
    *(uint2*)&outb[(size_t)v * NFEAT + slice * 64 + hl * 4] = pk.q2;
  }
}

// ---- thin GEMM: Gb[v][16](bf16) = dis[v] * (Ab[v] @ Wf), Ab bf16 row-major ----

__global__ __launch_bounds__(256) void gemm_small(const ushort* __restrict__ Ab,
                                                  const float* __restrict__ Wf,
                                                  const float* __restrict__ dis,
                                                  ushort* __restrict__ Gb, int n) {
  __shared__ float Ws[NFEAT * NCP];  // 8 KB
  for (int i = threadIdx.x; i < NFEAT * NCP; i += 256) Ws[i] = Wf[i];
  __syncthreads();
  const int v = blockIdx.x * 256 + threadIdx.x;
  if (v >= n) return;
  float acc[NCP];
  #pragma unroll
  for (int c = 0; c < NCP; ++c) acc[c] = 0.f;
  #pragma unroll
  for (int p = 0; p < 8; ++p) {
    union { ushort us[16]; int4 q[2]; } a;
    const ushort* pl = Ab + (size_t)v * NFEAT + p * 16;
    a.q[0] = *(const int4*)pl;
    a.q[1] = *(const int4*)(pl + 8);
    #pragma unroll
    for (int j = 0; j < 16; ++j) {
      float av = bf2f(a.us[j]);
      int k = p * 16 + j;
      #pragma unroll
      for (int cq = 0; cq < NCP; cq += 4) {
        float4 w = *(const float4*)&Ws[k * NCP + cq];
        acc[cq + 0] += av * w.x;
        acc[cq + 1] += av * w.y;
        acc[cq + 2] += av * w.z;
        acc[cq + 3] += av * w.w;
      }
    }
  }
  const float dv = dis[v];
  union { ushort us[16]; int4 q[2]; } pk;
  #pragma unroll
  for (int c = 0; c < NCP; ++c) pk.us[c] = f2bf(acc[c] * dv);
  *(int4*)&Gb[(size_t)v * NCP + 0] = pk.q[0];
  *(int4*)&Gb[(size_t)v * NCP + 8] = pk.q[1];
}

// ---------------- fused aggregation over bf16 G (16 feats) + bias + log_softmax --------

__global__ __launch_bounds__(256) void agg_logits(const ushort* __restrict__ Gb,
                                                  const int* __restrict__ row_ptr,
                                                  const int* __restrict__ ev,
                                                  const float* __restrict__ dis,
                                                  const float* __restrict__ bf,
                                                  float* __restrict__ out, int n) {
  const int wave = threadIdx.x >> 6;
  const int lane = threadIdx.x & 63;
  const int v = blockIdx.x * 4 + wave;
  if (v >= n) return;
  const int beg = row_ptr[v], end = row_ptr[v + 1];
  const int g = lane >> 4;           // 4 edge groups
  const int f = lane & 15;           // feature (class) index
  float acc = 0.f;
  int e = beg + g;
  for (; e + 4 < end; e += 8) {
    int s0 = ev[e];
    int s1 = ev[e + 4];
    acc += bf2f(Gb[(size_t)s0 * NCP + f]) + bf2f(Gb[(size_t)s1 * NCP + f]);
  }
  for (; e < end; e += 4) {
    acc += bf2f(Gb[(size_t)ev[e] * NCP + f]);
  }
  acc += __shfl_xor(acc, 16);
  acc += __shfl_xor(acc, 32);
  float logit = dis[v] * acc + bf[f];
  float pv = (f < NCLS) ? logit : -INFINITY;
  float m = pv;
  #pragma unroll
  for (int s = 8; s >= 1; s >>= 1) m = fmaxf(m, __shfl_xor(m, s));
  float ex = (f < NCLS) ? expf(logit - m) : 0.f;
  float ssum = ex;
  #pragma unroll
  for (int s = 8; s >= 1; s >>= 1) ssum += __shfl_xor(ssum, s);
  float lse = m + logf(ssum);
  if (g == 0 && f < NCLS) out[(size_t)v * NCLS + f] = logit - lse;
}

// ---------------- launcher ----------------

extern "C" void kernel_launch(void* const* d_in, const int* in_sizes, int n_in,
                              void* d_out, int out_size, void* d_ws, size_t ws_size,
                              hipStream_t stream) {
  const float* x  = (const float*)d_in[0];
  const int*   ei = (const int*)d_in[1];
  const float* W1 = (const float*)d_in[2];
  const float* b1 = (const float*)d_in[3];
  const float* W2 = (const float*)d_in[4];
  const float* b2 = (const float*)d_in[5];
  const float* W3 = (const float*)d_in[6];
  const float* b3 = (const float*)d_in[7];
  const float* Wl = (const float*)d_in[8];
  const float* bl = (const float*)d_in[9];
  float* out = (float*)d_out;

  const int nN = in_sizes[0] / NFEAT;   // 100000
  const int nE = in_sizes[1] / 2;       // 1600000
  const int total = nN + nE;
  const int nbkt = (nN + BROW - 1) >> 9;          // 196
  const int nbBin = (total + BINC - 1) / BINC;
  const size_t pstride = (size_t)nN * 64;         // elements per 64-feat plane

  char* ws = (char*)d_ws;
  int*    bkt_cnt = (int*)ws;     ws += alignup(256 * 4);
  int*    bkt_off = (int*)ws;     ws += alignup(257 * 4);
  int*    gfront  = (int*)ws;     ws += alignup(256 * 4);
  int*    row_ptr = (int*)ws;     ws += alignup((size_t)(nN + 1) * 4);
  float*  dis     = (float*)ws;   ws += alignup((size_t)nN * 4);
  float*  Wf      = (float*)ws;   ws += alignup((size_t)NFEAT * NCP * 4);
  float*  bfv     = (float*)ws;   ws += alignup((size_t)NCP * 4);
  ushort* Wt1     = (ushort*)ws;  ws += alignup((size_t)NFEAT * NFEAT * 2);
  ushort* Wt2     = (ushort*)ws;  ws += alignup((size_t)NFEAT * NFEAT * 2);
  int2*   binned  = (int2*)ws;    ws += alignup((size_t)total * 8);
  int*    ev      = (int*)ws;     ws += alignup((size_t)total * 4);
  ushort* hbS     = (ushort*)ws;  ws += alignup((size_t)nN * NFEAT * 2);  // gemm out, 2 planes
  ushort* hbA     = (ushort*)ws;  ws += alignup((size_t)nN * NFEAT * 2);  // agg out, row-major
  ushort* Gb      = (ushort*)ws;  ws += alignup((size_t)nN * NCP * 2);    // folded logits bf16

  // ---- CSR build
  hipMemsetAsync(bkt_cnt, 0, 256 * sizeof(int), stream);
  bucket_hist<<<512, 256, 0, stream>>>(ei + nE, bkt_cnt, nE, nbkt);
  bkt_scan<<<1, 256, 0, stream>>>(bkt_cnt, bkt_off, gfront, nN, nbkt);
  bin_items<<<nbBin, 256, 0, stream>>>(ei, nE, total, nbkt, gfront, binned);
  bucket_finalize<<<nbkt, BROW, 0, stream>>>(binned, bkt_off, row_ptr, dis, ev, nN, nbkt);

  // ---- weight prep
  fold_weights<<<8, 256, 0, stream>>>(W3, Wl, b3, bl, Wf, bfv);
  prep_w2<<<128, 256, 0, stream>>>(W1, W2, Wt1, Wt2);

  const int gemm_grid = (nN + 63) / 64;
  const int node_grid = (nN + 3) / 4;
  const int agg_grid = node_grid * 2;             // slice = bid & 1

  // layer 1
  gemm_mfma<false><<<gemm_grid, 256, 0, stream>>>(x, nullptr, Wt1, dis, hbS, pstride, nN);
  aggregate<<<agg_grid, 256, 0, stream>>>(hbS, row_ptr, ev, dis, b1, hbA, pstride, 1, nN);
  // layer 2
  gemm_mfma<true><<<gemm_grid, 256, 0, stream>>>(nullptr, hbA, Wt2, dis, hbS, pstride, nN);
  aggregate<<<agg_grid, 256, 0, stream>>>(hbS, row_ptr, ev, dis, b2, hbA, pstride, 1, nN);
  // layer 3 folded with classifier
  gemm_small<<<(nN + 255) / 256, 256, 0, stream>>>(hbA, Wf, dis, Gb, nN);
  agg_logits<<<node_grid, 256, 0, stream>>>(Gb, row_ptr, ev, dis, bfv, out, nN);
}

// Round 12
// 353.221 us; speedup vs baseline: 1.1545x; 1.1545x over previous
//
#include <hip/hip_runtime.h>

#define NFEAT 128
#define NCLS  10
#define NCP   16    // padded class count
#define BROW  512   // rows per bucket
#define BINC  4096  // items per binning chunk
// packed binned item: s (17 bits, nN<131072) | dl (9 bits) << 17

static inline size_t alignup(size_t x) { return (x + 255) & ~size_t(255); }

// bf16 helpers (bit-level, RNE)
__device__ __forceinline__ ushort f2bf(float f) {
  uint x = __float_as_uint(f);
  return (ushort)((x + 0x7fffu + ((x >> 16) & 1u)) >> 16);
}
__device__ __forceinline__ float bf2f(ushort u) {
  return __uint_as_float(((uint)u) << 16);
}

typedef short bf16x8 __attribute__((ext_vector_type(8)));
typedef float f32x4 __attribute__((ext_vector_type(4)));

// ---------------- CSR build (bucketed, write-amplification-free) ----------------

__global__ __launch_bounds__(256) void bucket_hist(const int* __restrict__ dst,
                                                   int* __restrict__ bkt_cnt,
                                                   int e, int nbkt) {
  __shared__ int hist[256];
  for (int t = threadIdx.x; t < nbkt; t += 256) hist[t] = 0;
  __syncthreads();
  int i = blockIdx.x * 256 + threadIdx.x;
  int stride = gridDim.x * 256;
  for (; i < e; i += stride) atomicAdd(&hist[dst[i] >> 9], 1);
  __syncthreads();
  for (int t = threadIdx.x; t < nbkt; t += 256)
    if (hist[t]) atomicAdd(&bkt_cnt[t], hist[t]);
}

__global__ __launch_bounds__(256) void bkt_scan(const int* __restrict__ bkt_cnt,
                                                int* __restrict__ bkt_off,
                                                int* __restrict__ gfrontier,
                                                int n, int nbkt) {
  __shared__ int sbuf[256];
  const int t = threadIdx.x;
  int x = 0;
  if (t < nbkt) {
    int lo = t << 9;
    int nodes = n - lo; if (nodes > BROW) nodes = BROW;
    x = bkt_cnt[t] + nodes;
  }
  sbuf[t] = x;
  __syncthreads();
  for (int off = 1; off < 256; off <<= 1) {
    int v = (t >= off) ? sbuf[t - off] : 0;
    __syncthreads();
    sbuf[t] += v;
    __syncthreads();
  }
  if (t < nbkt) { bkt_off[t] = sbuf[t] - x; gfrontier[t] = sbuf[t] - x; }
  if (t == nbkt - 1) bkt_off[nbkt] = sbuf[t];
}

__global__ __launch_bounds__(256) void bin_items(const int* __restrict__ ei,
                                                 int nE, int total, int nbkt,
                                                 int* __restrict__ gfrontier,
                                                 uint* __restrict__ binned) {
  __shared__ int hist[256];
  __shared__ int loff[256];
  __shared__ int gbase[256];
  __shared__ int sbuf[256];
  __shared__ int2 st[BINC];
  const int t = threadIdx.x;
  const int chunk0 = blockIdx.x * BINC;
  for (int q = t; q < nbkt; q += 256) hist[q] = 0;
  __syncthreads();
  for (int j = t; j < BINC; j += 256) {
    int i = chunk0 + j;
    if (i < total) {
      int d = (i < nE) ? ei[nE + i] : (i - nE);
      atomicAdd(&hist[d >> 9], 1);
    }
  }
  __syncthreads();
  int x = (t < nbkt) ? hist[t] : 0;
  sbuf[t] = x;
  __syncthreads();
  for (int off = 1; off < 256; off <<= 1) {
    int v = (t >= off) ? sbuf[t - off] : 0;
    __syncthreads();
    sbuf[t] += v;
    __syncthreads();
  }
  loff[t] = sbuf[t] - x;
  gbase[t] = (t < nbkt && x > 0) ? atomicAdd(&gfrontier[t], x) : 0;
  __syncthreads();
  hist[t] = loff[t];
  __syncthreads();
  for (int j = t; j < BINC; j += 256) {
    int i = chunk0 + j;
    if (i < total) {
      int s, d;
      if (i < nE) { s = ei[i]; d = ei[nE + i]; }
      else        { s = i - nE; d = s; }
      int p = atomicAdd(&hist[d >> 9], 1);
      st[p] = make_int2(s, d);
    }
  }
  __syncthreads();
  int M = total - chunk0; if (M > BINC) M = BINC;
  for (int j = t; j < M; j += 256) {
    int2 it = st[j];
    int b = it.y >> 9;
    uint pk = (uint)it.x | ((uint)(it.y & 511) << 17);
    binned[gbase[b] + (j - loff[b])] = pk;
  }
}

__global__ __launch_bounds__(512) void bucket_finalize(const uint* __restrict__ binned,
                                                       const int* __restrict__ bkt_off,
                                                       int* __restrict__ row_ptr,
                                                       float* __restrict__ dis,
                                                       int* __restrict__ ev,
                                                       int n, int nbkt) {
  __shared__ int hist[BROW];
  __shared__ int sbuf[BROW];
  __shared__ int pre[BROW];
  __shared__ int front[BROW];
  const int b = blockIdx.x;
  const int t = threadIdx.x;
  const int row0 = b << 9;
  const int beg = bkt_off[b], end = bkt_off[b + 1];
  hist[t] = 0; front[t] = 0;
  __syncthreads();
  for (int j = beg + t; j < end; j += BROW)
    atomicAdd(&hist[binned[j] >> 17], 1);
  __syncthreads();
  const int x = hist[t];
  const int v = row0 + t;
  if (v < n) dis[v] = rsqrtf((float)x);
  sbuf[t] = x;
  __syncthreads();
  for (int off = 1; off < BROW; off <<= 1) {
    int val = (t >= off) ? sbuf[t - off] : 0;
    __syncthreads();
    sbuf[t] += val;
    __syncthreads();
  }
  pre[t] = sbuf[t] - x;
  if (v < n) row_ptr[v] = beg + pre[t];
  if (b == nbkt - 1 && t == 0) row_ptr[n] = end;
  __syncthreads();
  for (int j = beg + t; j < end; j += BROW) {
    uint pk = binned[j];
    int dl = pk >> 17;
    int slot = atomicAdd(&front[dl], 1);
    ev[beg + pre[dl] + slot] = (int)(pk & 0x1FFFFu);
  }
}

// ---------------- weight prep (single launch) ----------------
// blocks 0..7:   Wf[r][c](fp32) = (W3@Wl)[r][c]; bf[c] = (b3@Wl+bl)[c]
// blocks 8..135: Wt1/Wt2[n][k](bf16) = W1/W2[k][n]

__global__ __launch_bounds__(256) void prep_all(const float* __restrict__ W1,
                                                const float* __restrict__ W2,
                                                const float* __restrict__ W3,
                                                const float* __restrict__ Wl,
                                                const float* __restrict__ b3,
                                                const float* __restrict__ bl,
                                                ushort* __restrict__ Wt1,
                                                ushort* __restrict__ Wt2,
                                                float* __restrict__ Wf,
                                                float* __restrict__ bf) {
  const int bid = blockIdx.x;
  if (bid < 8) {
    int t = bid * 256 + threadIdx.x;      // 0..2047 = NFEAT*NCP
    int r = t >> 4, c = t & 15;
    float s = 0.f;
    if (c < NCLS) {
      for (int k = 0; k < NFEAT; ++k) s += W3[r * NFEAT + k] * Wl[k * NCLS + c];
    }
    Wf[t] = s;
    if (t < NCP) {
      float sb = 0.f;
      if (t < NCLS) {
        sb = bl[t];
        for (int k = 0; k < NFEAT; ++k) sb += b3[k] * Wl[k * NCLS + t];
      }
      bf[t] = sb;
    }
  } else {
    int t = (bid - 8) * 256 + threadIdx.x;   // 0..32767
    int u = t & 16383;
    int n = u >> 7, k = u & 127;
    if (t < 16384) Wt1[n * NFEAT + k] = f2bf(W1[k * NFEAT + n]);
    else           Wt2[n * NFEAT + k] = f2bf(W2[k * NFEAT + n]);
  }
}

// ---- MFMA GEMM: Cb[r](bf16 row-major) = dis[r] * (A[r] @ W) ----
// BF16IN=false: A fp32 row-major. BF16IN=true: Ab bf16 row-major.

template<bool BF16IN>
__global__ __launch_bounds__(256) void gemm_mfma(const float* __restrict__ A,
                                                 const ushort* __restrict__ Ab,
                                                 const ushort* __restrict__ Wt,
                                                 const float* __restrict__ dis,
                                                 ushort* __restrict__ Cb, int nrows) {
  __shared__ __align__(16) ushort Asm[64 * NFEAT];   // 16 KB
  const int tid = threadIdx.x;
  const int row0 = blockIdx.x * 64;
  {
    const int m = tid >> 2;
    const int kc = (tid & 3) * 32;
    const int gr = row0 + m;
    int4 u[4];
    if (BF16IN) {
      if (gr < nrows) {
        const ushort* p = Ab + (size_t)gr * NFEAT + kc;
        u[0] = *(const int4*)(p + 0);
        u[1] = *(const int4*)(p + 8);
        u[2] = *(const int4*)(p + 16);
        u[3] = *(const int4*)(p + 24);
      } else {
        u[0] = u[1] = u[2] = u[3] = make_int4(0, 0, 0, 0);
      }
    } else {
      float4 f[8];
      if (gr < nrows) {
        #pragma unroll
        for (int q = 0; q < 8; ++q)
          f[q] = *(const float4*)&A[(size_t)gr * NFEAT + kc + q * 4];
      } else {
        #pragma unroll
        for (int q = 0; q < 8; ++q) f[q] = make_float4(0.f, 0.f, 0.f, 0.f);
      }
      #pragma unroll
      for (int q = 0; q < 4; ++q) {
        union { ushort us[8]; int4 v; } pk;
        const float* fp = (const float*)&f[q * 2];
        #pragma unroll
        for (int j = 0; j < 8; ++j) pk.us[j] = f2bf(fp[j]);
        u[q] = pk.v;
      }
    }
    #pragma unroll
    for (int q = 0; q < 4; ++q) {
      int byte = (m * 256 + (kc + q * 8) * 2) ^ ((m & 7) << 4);
      *(int4*)((char*)Asm + byte) = u[q];
    }
  }
  __syncthreads();
  const int wave = tid >> 6;
  const int lane = tid & 63;
  const int m0 = wave * 16;
  bf16x8 afr[4];
  #pragma unroll
  for (int ks = 0; ks < 4; ++ks) {
    int m = m0 + (lane & 15);
    int kk = ks * 32 + (lane >> 4) * 8;
    int byte = (m * 256 + kk * 2) ^ ((m & 7) << 4);
    afr[ks] = *(const bf16x8*)((const char*)Asm + byte);
  }
  f32x4 acc[8];
  #pragma unroll
  for (int c = 0; c < 8; ++c) acc[c] = (f32x4){0.f, 0.f, 0.f, 0.f};
  #pragma unroll
  for (int c = 0; c < 8; ++c) {
    #pragma unroll
    for (int ks = 0; ks < 4; ++ks) {
      int n = c * 16 + (lane & 15);
      int kk = ks * 32 + (lane >> 4) * 8;
      bf16x8 bfr = *(const bf16x8*)&Wt[n * NFEAT + kk];
      acc[c] = __builtin_amdgcn_mfma_f32_16x16x32_bf16(afr[ks], bfr, acc[c], 0, 0, 0);
    }
  }
  const int gr_base = row0 + m0 + (lane >> 4) * 4;
  float dr[4];
  #pragma unroll
  for (int r = 0; r < 4; ++r)
    dr[r] = (gr_base + r < nrows) ? dis[gr_base + r] : 0.f;
  #pragma unroll
  for (int c = 0; c < 8; ++c) {
    #pragma unroll
    for (int r = 0; r < 4; ++r) {
      int gr = gr_base + r;
      if (gr < nrows)
        Cb[(size_t)gr * NFEAT + c * 16 + (lane & 15)] = f2bf(acc[c][r] * dr[r]);
    }
  }
}

// ------- sparse aggregation: outb[v] = bf16(relu?(dis[v]*Σ h'[src] + bias)) -------
// round-9 verified shape: half-wave ushort4, 4 edges/half/iter -> 8 gathers in flight.

__global__ __launch_bounds__(256) void aggregate(const ushort* __restrict__ hw,
                                                 const int* __restrict__ row_ptr,
                                                 const int* __restrict__ ev,
                                                 const float* __restrict__ dis,
                                                 const float* __restrict__ bias,
                                                 ushort* __restrict__ outb,
                                                 int relu, int n) {
  const int wave = threadIdx.x >> 6;
  const int lane = threadIdx.x & 63;
  const int v = blockIdx.x * 4 + wave;
  if (v >= n) return;
  const int beg = row_ptr[v], end = row_ptr[v + 1];
  const int half = lane >> 5;        // 0/1: edge parity handled by this half-wave
  const int hl = lane & 31;          // feature group: feats hl*4 .. hl*4+3
  float4 acc = make_float4(0.f, 0.f, 0.f, 0.f);
  int e = beg + half;
  for (; e + 6 < end; e += 8) {      // 4 edges per half per iter -> 8 gathers in flight
    int s0 = ev[e];
    int s1 = ev[e + 2];
    int s2 = ev[e + 4];
    int s3 = ev[e + 6];
    ushort4 q0 = *(const ushort4*)&hw[(size_t)s0 * NFEAT + hl * 4];
    ushort4 q1 = *(const ushort4*)&hw[(size_t)s1 * NFEAT + hl * 4];
    ushort4 q2 = *(const ushort4*)&hw[(size_t)s2 * NFEAT + hl * 4];
    ushort4 q3 = *(const ushort4*)&hw[(size_t)s3 * NFEAT + hl * 4];
    acc.x += bf2f(q0.x) + bf2f(q1.x) + bf2f(q2.x) + bf2f(q3.x);
    acc.y += bf2f(q0.y) + bf2f(q1.y) + bf2f(q2.y) + bf2f(q3.y);
    acc.z += bf2f(q0.z) + bf2f(q1.z) + bf2f(q2.z) + bf2f(q3.z);
    acc.w += bf2f(q0.w) + bf2f(q1.w) + bf2f(q2.w) + bf2f(q3.w);
  }
  for (; e < end; e += 2) {
    int s = ev[e];
    ushort4 q = *(const ushort4*)&hw[(size_t)s * NFEAT + hl * 4];
    acc.x += bf2f(q.x); acc.y += bf2f(q.y);
    acc.z += bf2f(q.z); acc.w += bf2f(q.w);
  }
  acc.x += __shfl_xor(acc.x, 32);
  acc.y += __shfl_xor(acc.y, 32);
  acc.z += __shfl_xor(acc.z, 32);
  acc.w += __shfl_xor(acc.w, 32);
  if (half == 0) {
    float dv = dis[v];
    float4 b = *(const float4*)&bias[hl * 4];
    acc.x = fmaf(acc.x, dv, b.x); acc.y = fmaf(acc.y, dv, b.y);
    acc.z = fmaf(acc.z, dv, b.z); acc.w = fmaf(acc.w, dv, b.w);
    if (relu) {
      acc.x = fmaxf(acc.x, 0.f); acc.y = fmaxf(acc.y, 0.f);
      acc.z = fmaxf(acc.z, 0.f); acc.w = fmaxf(acc.w, 0.f);
    }
    union { ushort us[4]; uint2 q2; } pk;
    pk.us[0] = f2bf(acc.x); pk.us[1] = f2bf(acc.y);
    pk.us[2] = f2bf(acc.z); pk.us[3] = f2bf(acc.w);
    *(uint2*)&outb[(size_t)v * NFEAT + hl * 4] = pk.q2;
  }
}

// ---- thin GEMM: Gb[v][16](bf16) = dis[v] * (Ab[v] @ Wf), Ab bf16 row-major ----

__global__ __launch_bounds__(256) void gemm_small(const ushort* __restrict__ Ab,
                                                  const float* __restrict__ Wf,
                                                  const float* __restrict__ dis,
                                                  ushort* __restrict__ Gb, int n) {
  __shared__ float Ws[NFEAT * NCP];  // 8 KB
  for (int i = threadIdx.x; i < NFEAT * NCP; i += 256) Ws[i] = Wf[i];
  __syncthreads();
  const int v = blockIdx.x * 256 + threadIdx.x;
  if (v >= n) return;
  float acc[NCP];
  #pragma unroll
  for (int c = 0; c < NCP; ++c) acc[c] = 0.f;
  #pragma unroll
  for (int p = 0; p < 8; ++p) {
    union { ushort us[16]; int4 q[2]; } a;
    const ushort* pl = Ab + (size_t)v * NFEAT + p * 16;
    a.q[0] = *(const int4*)pl;
    a.q[1] = *(const int4*)(pl + 8);
    #pragma unroll
    for (int j = 0; j < 16; ++j) {
      float av = bf2f(a.us[j]);
      int k = p * 16 + j;
      #pragma unroll
      for (int cq = 0; cq < NCP; cq += 4) {
        float4 w = *(const float4*)&Ws[k * NCP + cq];
        acc[cq + 0] += av * w.x;
        acc[cq + 1] += av * w.y;
        acc[cq + 2] += av * w.z;
        acc[cq + 3] += av * w.w;
      }
    }
  }
  const float dv = dis[v];
  union { ushort us[16]; int4 q[2]; } pk;
  #pragma unroll
  for (int c = 0; c < NCP; ++c) pk.us[c] = f2bf(acc[c] * dv);
  *(int4*)&Gb[(size_t)v * NCP + 0] = pk.q[0];
  *(int4*)&Gb[(size_t)v * NCP + 8] = pk.q[1];
}

// ---------------- fused aggregation over bf16 G (16 feats) + bias + log_softmax --------

__global__ __launch_bounds__(256) void agg_logits(const ushort* __restrict__ Gb,
                                                  const int* __restrict__ row_ptr,
                                                  const int* __restrict__ ev,
                                                  const float* __restrict__ dis,
                                                  const float* __restrict__ bf,
                                                  float* __restrict__ out, int n) {
  const int wave = threadIdx.x >> 6;
  const int lane = threadIdx.x & 63;
  const int v = blockIdx.x * 4 + wave;
  if (v >= n) return;
  const int beg = row_ptr[v], end = row_ptr[v + 1];
  const int g = lane >> 4;           // 4 edge groups
  const int f = lane & 15;           // feature (class) index
  float acc = 0.f;
  int e = beg + g;
  for (; e + 4 < end; e += 8) {
    int s0 = ev[e];
    int s1 = ev[e + 4];
    acc += bf2f(Gb[(size_t)s0 * NCP + f]) + bf2f(Gb[(size_t)s1 * NCP + f]);
  }
  for (; e < end; e += 4) {
    acc += bf2f(Gb[(size_t)ev[e] * NCP + f]);
  }
  acc += __shfl_xor(acc, 16);
  acc += __shfl_xor(acc, 32);
  float logit = dis[v] * acc + bf[f];
  float pv = (f < NCLS) ? logit : -INFINITY;
  float m = pv;
  #pragma unroll
  for (int s = 8; s >= 1; s >>= 1) m = fmaxf(m, __shfl_xor(m, s));
  float ex = (f < NCLS) ? expf(logit - m) : 0.f;
  float ssum = ex;
  #pragma unroll
  for (int s = 8; s >= 1; s >>= 1) ssum += __shfl_xor(ssum, s);
  float lse = m + logf(ssum);
  if (g == 0 && f < NCLS) out[(size_t)v * NCLS + f] = logit - lse;
}

// ---------------- launcher ----------------

extern "C" void kernel_launch(void* const* d_in, const int* in_sizes, int n_in,
                              void* d_out, int out_size, void* d_ws, size_t ws_size,
                              hipStream_t stream) {
  const float* x  = (const float*)d_in[0];
  const int*   ei = (const int*)d_in[1];
  const float* W1 = (const float*)d_in[2];
  const float* b1 = (const float*)d_in[3];
  const float* W2 = (const float*)d_in[4];
  const float* b2 = (const float*)d_in[5];
  const float* W3 = (const float*)d_in[6];
  const float* b3 = (const float*)d_in[7];
  const float* Wl = (const float*)d_in[8];
  const float* bl = (const float*)d_in[9];
  float* out = (float*)d_out;

  const int nN = in_sizes[0] / NFEAT;   // 100000
  const int nE = in_sizes[1] / 2;       // 1600000
  const int total = nN + nE;
  const int nbkt = (nN + BROW - 1) >> 9;          // 196
  const int nbBin = (total + BINC - 1) / BINC;

  char* ws = (char*)d_ws;
  int*    bkt_cnt = (int*)ws;     ws += alignup(256 * 4);
  int*    bkt_off = (int*)ws;     ws += alignup(257 * 4);
  int*    gfront  = (int*)ws;     ws += alignup(256 * 4);
  int*    row_ptr = (int*)ws;     ws += alignup((size_t)(nN + 1) * 4);
  float*  dis     = (float*)ws;   ws += alignup((size_t)nN * 4);
  float*  Wf      = (float*)ws;   ws += alignup((size_t)NFEAT * NCP * 4);
  float*  bfv     = (float*)ws;   ws += alignup((size_t)NCP * 4);
  ushort* Wt1     = (ushort*)ws;  ws += alignup((size_t)NFEAT * NFEAT * 2);
  ushort* Wt2     = (ushort*)ws;  ws += alignup((size_t)NFEAT * NFEAT * 2);
  uint*   binned  = (uint*)ws;    ws += alignup((size_t)total * 4);
  int*    ev      = (int*)ws;     ws += alignup((size_t)total * 4);
  ushort* hb      = (ushort*)ws;  ws += alignup((size_t)nN * NFEAT * 2);  // gemm out (bf16 rows)
  ushort* hbA     = (ushort*)ws;  ws += alignup((size_t)nN * NFEAT * 2);  // agg out (bf16 rows)
  ushort* Gb      = (ushort*)ws;  ws += alignup((size_t)nN * NCP * 2);    // folded logits (bf16)

  // ---- CSR build
  hipMemsetAsync(bkt_cnt, 0, 256 * sizeof(int), stream);
  bucket_hist<<<512, 256, 0, stream>>>(ei + nE, bkt_cnt, nE, nbkt);
  bkt_scan<<<1, 256, 0, stream>>>(bkt_cnt, bkt_off, gfront, nN, nbkt);
  bin_items<<<nbBin, 256, 0, stream>>>(ei, nE, total, nbkt, gfront, binned);
  bucket_finalize<<<nbkt, BROW, 0, stream>>>(binned, bkt_off, row_ptr, dis, ev, nN, nbkt);

  // ---- weight prep (single launch)
  prep_all<<<136, 256, 0, stream>>>(W1, W2, W3, Wl, b3, bl, Wt1, Wt2, Wf, bfv);

  const int gemm_grid = (nN + 63) / 64;
  const int node_grid = (nN + 3) / 4;

  // layer 1
  gemm_mfma<false><<<gemm_grid, 256, 0, stream>>>(x, nullptr, Wt1, dis, hb, nN);
  aggregate<<<node_grid, 256, 0, stream>>>(hb, row_ptr, ev, dis, b1, hbA, 1, nN);
  // layer 2
  gemm_mfma<true><<<gemm_grid, 256, 0, stream>>>(nullptr, hbA, Wt2, dis, hb, nN);
  aggregate<<<node_grid, 256, 0, stream>>>(hb, row_ptr, ev, dis, b2, hbA, 1, nN);
  // layer 3 folded with classifier
  gemm_small<<<(nN + 255) / 256, 256, 0, stream>>>(hbA, Wf, dis, Gb, nN);
  agg_logits<<<node_grid, 256, 0, stream>>>(Gb, row_ptr, ev, dis, bfv, out, nN);
}

// Round 13
// 341.205 us; speedup vs baseline: 1.1951x; 1.0352x over previous
//
#include <hip/hip_runtime.h>

#define NFEAT 128
#define NCLS  10
#define NCP   16    // padded class count
#define BROW  512   // rows per bucket
#define BINC  4096  // items per binning chunk
// packed binned item: s (17 bits, nN<131072) | dl (9 bits) << 17

static inline size_t alignup(size_t x) { return (x + 255) & ~size_t(255); }

// bf16 helpers (bit-level, RNE)
__device__ __forceinline__ ushort f2bf(float f) {
  uint x = __float_as_uint(f);
  return (ushort)((x + 0x7fffu + ((x >> 16) & 1u)) >> 16);
}
__device__ __forceinline__ float bf2f(ushort u) {
  return __uint_as_float(((uint)u) << 16);
}

typedef short bf16x8 __attribute__((ext_vector_type(8)));
typedef float f32x4 __attribute__((ext_vector_type(4)));

// ---------------- CSR build (bucketed, write-amplification-free) ----------------

// blocks 0..511: bucket histogram. blocks 512..647: weight prep (fused to save a launch).
__global__ __launch_bounds__(256) void hist_prep(const int* __restrict__ dst,
                                                 int* __restrict__ bkt_cnt,
                                                 int e, int nbkt,
                                                 const float* __restrict__ W1,
                                                 const float* __restrict__ W2,
                                                 const float* __restrict__ W3,
                                                 const float* __restrict__ Wl,
                                                 const float* __restrict__ b3,
                                                 const float* __restrict__ bl,
                                                 ushort* __restrict__ Wt1,
                                                 ushort* __restrict__ Wt2,
                                                 float* __restrict__ Wf,
                                                 float* __restrict__ bf) {
  const int bid = blockIdx.x;
  if (bid >= 512) {
    const int pb = bid - 512;
    if (pb < 8) {
      int t = pb * 256 + threadIdx.x;      // 0..2047 = NFEAT*NCP
      int r = t >> 4, c = t & 15;
      float s = 0.f;
      if (c < NCLS) {
        for (int k = 0; k < NFEAT; ++k) s += W3[r * NFEAT + k] * Wl[k * NCLS + c];
      }
      Wf[t] = s;
      if (t < NCP) {
        float sb = 0.f;
        if (t < NCLS) {
          sb = bl[t];
          for (int k = 0; k < NFEAT; ++k) sb += b3[k] * Wl[k * NCLS + t];
        }
        bf[t] = sb;
      }
    } else {
      int t = (pb - 8) * 256 + threadIdx.x;   // 0..32767
      int u = t & 16383;
      int n = u >> 7, k = u & 127;
      if (t < 16384) Wt1[n * NFEAT + k] = f2bf(W1[k * NFEAT + n]);
      else           Wt2[n * NFEAT + k] = f2bf(W2[k * NFEAT + n]);
    }
    return;
  }
  __shared__ int hist[256];
  for (int t = threadIdx.x; t < nbkt; t += 256) hist[t] = 0;
  __syncthreads();
  int i = bid * 256 + threadIdx.x;
  const int stride = 512 * 256;
  for (; i < e; i += stride) atomicAdd(&hist[dst[i] >> 9], 1);
  __syncthreads();
  for (int t = threadIdx.x; t < nbkt; t += 256)
    if (hist[t]) atomicAdd(&bkt_cnt[t], hist[t]);
}

__global__ __launch_bounds__(256) void bkt_scan(const int* __restrict__ bkt_cnt,
                                                int* __restrict__ bkt_off,
                                                int* __restrict__ gfrontier,
                                                int n, int nbkt) {
  __shared__ int wsum[4];
  const int t = threadIdx.x;
  const int lane = t & 63, wv = t >> 6;
  int x = 0;
  if (t < nbkt) {
    int lo = t << 9;
    int nodes = n - lo; if (nodes > BROW) nodes = BROW;
    x = bkt_cnt[t] + nodes;
  }
  int xs = x;
  #pragma unroll
  for (int off = 1; off < 64; off <<= 1) {
    int y = __shfl_up(xs, off);
    if (lane >= off) xs += y;
  }
  if (lane == 63) wsum[wv] = xs;
  __syncthreads();
  int add = 0;
  if (wv > 0) add += wsum[0];
  if (wv > 1) add += wsum[1];
  if (wv > 2) add += wsum[2];
  int incl = xs + add;
  if (t < nbkt) { bkt_off[t] = incl - x; gfrontier[t] = incl - x; }
  if (t == nbkt - 1) bkt_off[nbkt] = incl;
}

__global__ __launch_bounds__(256) void bin_items(const int* __restrict__ ei,
                                                 int nE, int total, int nbkt,
                                                 int* __restrict__ gfrontier,
                                                 uint* __restrict__ binned) {
  __shared__ int hist[256];
  __shared__ int loff[256];
  __shared__ int gbase[256];
  __shared__ int wsum[4];
  __shared__ int2 st[BINC];
  const int t = threadIdx.x;
  const int lane = t & 63, wv = t >> 6;
  const int chunk0 = blockIdx.x * BINC;
  for (int q = t; q < nbkt; q += 256) hist[q] = 0;
  __syncthreads();
  for (int j = t; j < BINC; j += 256) {
    int i = chunk0 + j;
    if (i < total) {
      int d = (i < nE) ? ei[nE + i] : (i - nE);
      atomicAdd(&hist[d >> 9], 1);
    }
  }
  __syncthreads();
  int x = (t < nbkt) ? hist[t] : 0;
  int xs = x;
  #pragma unroll
  for (int off = 1; off < 64; off <<= 1) {
    int y = __shfl_up(xs, off);
    if (lane >= off) xs += y;
  }
  if (lane == 63) wsum[wv] = xs;
  __syncthreads();
  int add = 0;
  if (wv > 0) add += wsum[0];
  if (wv > 1) add += wsum[1];
  if (wv > 2) add += wsum[2];
  loff[t] = xs + add - x;
  gbase[t] = (t < nbkt && x > 0) ? atomicAdd(&gfrontier[t], x) : 0;
  hist[t] = loff[t];          // own-index overwrite; all cross-thread reads of hist done
  __syncthreads();
  for (int j = t; j < BINC; j += 256) {
    int i = chunk0 + j;
    if (i < total) {
      int s, d;
      if (i < nE) { s = ei[i]; d = ei[nE + i]; }
      else        { s = i - nE; d = s; }
      int p = atomicAdd(&hist[d >> 9], 1);
      st[p] = make_int2(s, d);
    }
  }
  __syncthreads();
  int M = total - chunk0; if (M > BINC) M = BINC;
  for (int j = t; j < M; j += 256) {
    int2 it = st[j];
    int b = it.y >> 9;
    uint pk = (uint)it.x | ((uint)(it.y & 511) << 17);
    binned[gbase[b] + (j - loff[b])] = pk;
  }
}

__global__ __launch_bounds__(512) void bucket_finalize(const uint* __restrict__ binned,
                                                       const int* __restrict__ bkt_off,
                                                       int* __restrict__ row_ptr,
                                                       float* __restrict__ dis,
                                                       int* __restrict__ ev,
                                                       int n, int nbkt) {
  __shared__ int hist[BROW];
  __shared__ int pre[BROW];
  __shared__ int front[BROW];
  __shared__ int wsum[8];
  const int b = blockIdx.x;
  const int t = threadIdx.x;
  const int lane = t & 63, wv = t >> 6;
  const int row0 = b << 9;
  const int beg = bkt_off[b], end = bkt_off[b + 1];
  hist[t] = 0; front[t] = 0;
  __syncthreads();
  for (int j = beg + t; j < end; j += BROW)
    atomicAdd(&hist[binned[j] >> 17], 1);
  __syncthreads();
  const int x = hist[t];
  const int v = row0 + t;
  if (v < n) dis[v] = rsqrtf((float)x);
  int xs = x;
  #pragma unroll
  for (int off = 1; off < 64; off <<= 1) {
    int y = __shfl_up(xs, off);
    if (lane >= off) xs += y;
  }
  if (lane == 63) wsum[wv] = xs;
  __syncthreads();
  int add = 0;
  #pragma unroll
  for (int w = 0; w < 7; ++w)
    if (w < wv) add += wsum[w];
  pre[t] = xs + add - x;
  if (v < n) row_ptr[v] = beg + pre[t];
  if (b == nbkt - 1 && t == 0) row_ptr[n] = end;
  __syncthreads();
  for (int j = beg + t; j < end; j += BROW) {
    uint pk = binned[j];
    int dl = pk >> 17;
    int slot = atomicAdd(&front[dl], 1);
    ev[beg + pre[dl] + slot] = (int)(pk & 0x1FFFFu);
  }
}

// ---- MFMA GEMM: Cb[r](bf16 row-major) = dis[r] * (A[r] @ W) ----
// BF16IN=false: A fp32 row-major. BF16IN=true: Ab bf16 row-major.

template<bool BF16IN>
__global__ __launch_bounds__(256) void gemm_mfma(const float* __restrict__ A,
                                                 const ushort* __restrict__ Ab,
                                                 const ushort* __restrict__ Wt,
                                                 const float* __restrict__ dis,
                                                 ushort* __restrict__ Cb, int nrows) {
  __shared__ __align__(16) ushort Asm[64 * NFEAT];   // 16 KB
  const int tid = threadIdx.x;
  const int row0 = blockIdx.x * 64;
  {
    const int m = tid >> 2;
    const int kc = (tid & 3) * 32;
    const int gr = row0 + m;
    int4 u[4];
    if (BF16IN) {
      if (gr < nrows) {
        const ushort* p = Ab + (size_t)gr * NFEAT + kc;
        u[0] = *(const int4*)(p + 0);
        u[1] = *(const int4*)(p + 8);
        u[2] = *(const int4*)(p + 16);
        u[3] = *(const int4*)(p + 24);
      } else {
        u[0] = u[1] = u[2] = u[3] = make_int4(0, 0, 0, 0);
      }
    } else {
      float4 f[8];
      if (gr < nrows) {
        #pragma unroll
        for (int q = 0; q < 8; ++q)
          f[q] = *(const float4*)&A[(size_t)gr * NFEAT + kc + q * 4];
      } else {
        #pragma unroll
        for (int q = 0; q < 8; ++q) f[q] = make_float4(0.f, 0.f, 0.f, 0.f);
      }
      #pragma unroll
      for (int q = 0; q < 4; ++q) {
        union { ushort us[8]; int4 v; } pk;
        const float* fp = (const float*)&f[q * 2];
        #pragma unroll
        for (int j = 0; j < 8; ++j) pk.us[j] = f2bf(fp[j]);
        u[q] = pk.v;
      }
    }
    #pragma unroll
    for (int q = 0; q < 4; ++q) {
      int byte = (m * 256 + (kc + q * 8) * 2) ^ ((m & 7) << 4);
      *(int4*)((char*)Asm + byte) = u[q];
    }
  }
  __syncthreads();
  const int wave = tid >> 6;
  const int lane = tid & 63;
  const int m0 = wave * 16;
  bf16x8 afr[4];
  #pragma unroll
  for (int ks = 0; ks < 4; ++ks) {
    int m = m0 + (lane & 15);
    int kk = ks * 32 + (lane >> 4) * 8;
    int byte = (m * 256 + kk * 2) ^ ((m & 7) << 4);
    afr[ks] = *(const bf16x8*)((const char*)Asm + byte);
  }
  f32x4 acc[8];
  #pragma unroll
  for (int c = 0; c < 8; ++c) acc[c] = (f32x4){0.f, 0.f, 0.f, 0.f};
  #pragma unroll
  for (int c = 0; c < 8; ++c) {
    #pragma unroll
    for (int ks = 0; ks < 4; ++ks) {
      int n = c * 16 + (lane & 15);
      int kk = ks * 32 + (lane >> 4) * 8;
      bf16x8 bfr = *(const bf16x8*)&Wt[n * NFEAT + kk];
      acc[c] = __builtin_amdgcn_mfma_f32_16x16x32_bf16(afr[ks], bfr, acc[c], 0, 0, 0);
    }
  }
  const int gr_base = row0 + m0 + (lane >> 4) * 4;
  float dr[4];
  #pragma unroll
  for (int r = 0; r < 4; ++r)
    dr[r] = (gr_base + r < nrows) ? dis[gr_base + r] : 0.f;
  #pragma unroll
  for (int c = 0; c < 8; ++c) {
    #pragma unroll
    for (int r = 0; r < 4; ++r) {
      int gr = gr_base + r;
      if (gr < nrows)
        Cb[(size_t)gr * NFEAT + c * 16 + (lane & 15)] = f2bf(acc[c][r] * dr[r]);
    }
  }
}

// ------- sparse aggregation: outb[v] = bf16(relu?(dis[v]*Σ h'[src] + bias)) -------
// half-wave ushort4; 8 edges/half/iter -> 16 gathers in flight/wave; CACHED ev loads
// (isolating the unroll variable from round 8's {unroll+nontemporal} regression).

__global__ __launch_bounds__(256) void aggregate(const ushort* __restrict__ hw,
                                                 const int* __restrict__ row_ptr,
                                                 const int* __restrict__ ev,
                                                 const float* __restrict__ dis,
                                                 const float* __restrict__ bias,
                                                 ushort* __restrict__ outb,
                                                 int relu, int n) {
  const int wave = threadIdx.x >> 6;
  const int lane = threadIdx.x & 63;
  const int v = blockIdx.x * 4 + wave;
  if (v >= n) return;
  const int beg = row_ptr[v], end = row_ptr[v + 1];
  const int half = lane >> 5;        // 0/1: edge parity handled by this half-wave
  const int hl = lane & 31;          // feature group: feats hl*4 .. hl*4+3
  float4 acc = make_float4(0.f, 0.f, 0.f, 0.f);
  int e = beg + half;
  for (; e + 14 < end; e += 16) {    // 8 edges per half per iter -> 16 gathers in flight
    int s0 = ev[e];
    int s1 = ev[e + 2];
    int s2 = ev[e + 4];
    int s3 = ev[e + 6];
    int s4 = ev[e + 8];
    int s5 = ev[e + 10];
    int s6 = ev[e + 12];
    int s7 = ev[e + 14];
    ushort4 q0 = *(const ushort4*)&hw[(size_t)s0 * NFEAT + hl * 4];
    ushort4 q1 = *(const ushort4*)&hw[(size_t)s1 * NFEAT + hl * 4];
    ushort4 q2 = *(const ushort4*)&hw[(size_t)s2 * NFEAT + hl * 4];
    ushort4 q3 = *(const ushort4*)&hw[(size_t)s3 * NFEAT + hl * 4];
    ushort4 q4 = *(const ushort4*)&hw[(size_t)s4 * NFEAT + hl * 4];
    ushort4 q5 = *(const ushort4*)&hw[(size_t)s5 * NFEAT + hl * 4];
    ushort4 q6 = *(const ushort4*)&hw[(size_t)s6 * NFEAT + hl * 4];
    ushort4 q7 = *(const ushort4*)&hw[(size_t)s7 * NFEAT + hl * 4];
    acc.x += (bf2f(q0.x) + bf2f(q1.x) + bf2f(q2.x) + bf2f(q3.x))
           + (bf2f(q4.x) + bf2f(q5.x) + bf2f(q6.x) + bf2f(q7.x));
    acc.y += (bf2f(q0.y) + bf2f(q1.y) + bf2f(q2.y) + bf2f(q3.y))
           + (bf2f(q4.y) + bf2f(q5.y) + bf2f(q6.y) + bf2f(q7.y));
    acc.z += (bf2f(q0.z) + bf2f(q1.z) + bf2f(q2.z) + bf2f(q3.z))
           + (bf2f(q4.z) + bf2f(q5.z) + bf2f(q6.z) + bf2f(q7.z));
    acc.w += (bf2f(q0.w) + bf2f(q1.w) + bf2f(q2.w) + bf2f(q3.w))
           + (bf2f(q4.w) + bf2f(q5.w) + bf2f(q6.w) + bf2f(q7.w));
  }
  for (; e + 6 < end; e += 8) {      // 4 edges per half
    int s0 = ev[e];
    int s1 = ev[e + 2];
    int s2 = ev[e + 4];
    int s3 = ev[e + 6];
    ushort4 q0 = *(const ushort4*)&hw[(size_t)s0 * NFEAT + hl * 4];
    ushort4 q1 = *(const ushort4*)&hw[(size_t)s1 * NFEAT + hl * 4];
    ushort4 q2 = *(const ushort4*)&hw[(size_t)s2 * NFEAT + hl * 4];
    ushort4 q3 = *(const ushort4*)&hw[(size_t)s3 * NFEAT + hl * 4];
    acc.x += bf2f(q0.x) + bf2f(q1.x) + bf2f(q2.x) + bf2f(q3.x);
    acc.y += bf2f(q0.y) + bf2f(q1.y) + bf2f(q2.y) + bf2f(q3.y);
    acc.z += bf2f(q0.z) + bf2f(q1.z) + bf2f(q2.z) + bf2f(q3.z);
    acc.w += bf2f(q0.w) + bf2f(q1.w) + bf2f(q2.w) + bf2f(q3.w);
  }
  for (; e < end; e += 2) {
    int s = ev[e];
    ushort4 q = *(const ushort4*)&hw[(size_t)s * NFEAT + hl * 4];
    acc.x += bf2f(q.x); acc.y += bf2f(q.y);
    acc.z += bf2f(q.z); acc.w += bf2f(q.w);
  }
  acc.x += __shfl_xor(acc.x, 32);
  acc.y += __shfl_xor(acc.y, 32);
  acc.z += __shfl_xor(acc.z, 32);
  acc.w += __shfl_xor(acc.w, 32);
  if (half == 0) {
    float dv = dis[v];
    float4 b = *(const float4*)&bias[hl * 4];
    acc.x = fmaf(acc.x, dv, b.x); acc.y = fmaf(acc.y, dv, b.y);
    acc.z = fmaf(acc.z, dv, b.z); acc.w = fmaf(acc.w, dv, b.w);
    if (relu) {
      acc.x = fmaxf(acc.x, 0.f); acc.y = fmaxf(acc.y, 0.f);
      acc.z = fmaxf(acc.z, 0.f); acc.w = fmaxf(acc.w, 0.f);
    }
    union { ushort us[4]; uint2 q2; } pk;
    pk.us[0] = f2bf(acc.x); pk.us[1] = f2bf(acc.y);
    pk.us[2] = f2bf(acc.z); pk.us[3] = f2bf(acc.w);
    *(uint2*)&outb[(size_t)v * NFEAT + hl * 4] = pk.q2;
  }
}

// ---- thin GEMM: Gb[v][16](bf16) = dis[v] * (Ab[v] @ Wf), Ab bf16 row-major ----

__global__ __launch_bounds__(256) void gemm_small(const ushort* __restrict__ Ab,
                                                  const float* __restrict__ Wf,
                                                  const float* __restrict__ dis,
                                                  ushort* __restrict__ Gb, int n) {
  __shared__ float Ws[NFEAT * NCP];  // 8 KB
  for (int i = threadIdx.x; i < NFEAT * NCP; i += 256) Ws[i] = Wf[i];
  __syncthreads();
  const int v = blockIdx.x * 256 + threadIdx.x;
  if (v >= n) return;
  float acc[NCP];
  #pragma unroll
  for (int c = 0; c < NCP; ++c) acc[c] = 0.f;
  #pragma unroll
  for (int p = 0; p < 8; ++p) {
    union { ushort us[16]; int4 q[2]; } a;
    const ushort* pl = Ab + (size_t)v * NFEAT + p * 16;
    a.q[0] = *(const int4*)pl;
    a.q[1] = *(const int4*)(pl + 8);
    #pragma unroll
    for (int j = 0; j < 16; ++j) {
      float av = bf2f(a.us[j]);
      int k = p * 16 + j;
      #pragma unroll
      for (int cq = 0; cq < NCP; cq += 4) {
        float4 w = *(const float4*)&Ws[k * NCP + cq];
        acc[cq + 0] += av * w.x;
        acc[cq + 1] += av * w.y;
        acc[cq + 2] += av * w.z;
        acc[cq + 3] += av * w.w;
      }
    }
  }
  const float dv = dis[v];
  union { ushort us[16]; int4 q[2]; } pk;
  #pragma unroll
  for (int c = 0; c < NCP; ++c) pk.us[c] = f2bf(acc[c] * dv);
  *(int4*)&Gb[(size_t)v * NCP + 0] = pk.q[0];
  *(int4*)&Gb[(size_t)v * NCP + 8] = pk.q[1];
}

// ---------------- fused aggregation over bf16 G (16 feats) + bias + log_softmax --------

__global__ __launch_bounds__(256) void agg_logits(const ushort* __restrict__ Gb,
                                                  const int* __restrict__ row_ptr,
                                                  const int* __restrict__ ev,
                                                  const float* __restrict__ dis,
                                                  const float* __restrict__ bf,
                                                  float* __restrict__ out, int n) {
  const int wave = threadIdx.x >> 6;
  const int lane = threadIdx.x & 63;
  const int v = blockIdx.x * 4 + wave;
  if (v >= n) return;
  const int beg = row_ptr[v], end = row_ptr[v + 1];
  const int g = lane >> 4;           // 4 edge groups
  const int f = lane & 15;           // feature (class) index
  float acc = 0.f;
  int e = beg + g;
  for (; e + 4 < end; e += 8) {
    int s0 = ev[e];
    int s1 = ev[e + 4];
    acc += bf2f(Gb[(size_t)s0 * NCP + f]) + bf2f(Gb[(size_t)s1 * NCP + f]);
  }
  for (; e < end; e += 4) {
    acc += bf2f(Gb[(size_t)ev[e] * NCP + f]);
  }
  acc += __shfl_xor(acc, 16);
  acc += __shfl_xor(acc, 32);
  float logit = dis[v] * acc + bf[f];
  float pv = (f < NCLS) ? logit : -INFINITY;
  float m = pv;
  #pragma unroll
  for (int s = 8; s >= 1; s >>= 1) m = fmaxf(m, __shfl_xor(m, s));
  float ex = (f < NCLS) ? expf(logit - m) : 0.f;
  float ssum = ex;
  #pragma unroll
  for (int s = 8; s >= 1; s >>= 1) ssum += __shfl_xor(ssum, s);
  float lse = m + logf(ssum);
  if (g == 0 && f < NCLS) out[(size_t)v * NCLS + f] = logit - lse;
}

// ---------------- launcher ----------------

extern "C" void kernel_launch(void* const* d_in, const int* in_sizes, int n_in,
                              void* d_out, int out_size, void* d_ws, size_t ws_size,
                              hipStream_t stream) {
  const float* x  = (const float*)d_in[0];
  const int*   ei = (const int*)d_in[1];
  const float* W1 = (const float*)d_in[2];
  const float* b1 = (const float*)d_in[3];
  const float* W2 = (const float*)d_in[4];
  const float* b2 = (const float*)d_in[5];
  const float* W3 = (const float*)d_in[6];
  const float* b3 = (const float*)d_in[7];
  const float* Wl = (const float*)d_in[8];
  const float* bl = (const float*)d_in[9];
  float* out = (float*)d_out;

  const int nN = in_sizes[0] / NFEAT;   // 100000
  const int nE = in_sizes[1] / 2;       // 1600000
  const int total = nN + nE;
  const int nbkt = (nN + BROW - 1) >> 9;          // 196
  const int nbBin = (total + BINC - 1) / BINC;

  char* ws = (char*)d_ws;
  int*    bkt_cnt = (int*)ws;     ws += alignup(256 * 4);
  int*    bkt_off = (int*)ws;     ws += alignup(257 * 4);
  int*    gfront  = (int*)ws;     ws += alignup(256 * 4);
  int*    row_ptr = (int*)ws;     ws += alignup((size_t)(nN + 1) * 4);
  float*  dis     = (float*)ws;   ws += alignup((size_t)nN * 4);
  float*  Wf      = (float*)ws;   ws += alignup((size_t)NFEAT * NCP * 4);
  float*  bfv     = (float*)ws;   ws += alignup((size_t)NCP * 4);
  ushort* Wt1     = (ushort*)ws;  ws += alignup((size_t)NFEAT * NFEAT * 2);
  ushort* Wt2     = (ushort*)ws;  ws += alignup((size_t)NFEAT * NFEAT * 2);
  uint*   binned  = (uint*)ws;    ws += alignup((size_t)total * 4);
  int*    ev      = (int*)ws;     ws += alignup((size_t)total * 4);
  ushort* hb      = (ushort*)ws;  ws += alignup((size_t)nN * NFEAT * 2);  // gemm out (bf16 rows)
  ushort* hbA     = (ushort*)ws;  ws += alignup((size_t)nN * NFEAT * 2);  // agg out (bf16 rows)
  ushort* Gb      = (ushort*)ws;  ws += alignup((size_t)nN * NCP * 2);    // folded logits (bf16)

  // ---- CSR build + weight prep (prep fused into hist grid)
  hipMemsetAsync(bkt_cnt, 0, 256 * sizeof(int), stream);
  hist_prep<<<648, 256, 0, stream>>>(ei + nE, bkt_cnt, nE, nbkt,
                                     W1, W2, W3, Wl, b3, bl, Wt1, Wt2, Wf, bfv);
  bkt_scan<<<1, 256, 0, stream>>>(bkt_cnt, bkt_off, gfront, nN, nbkt);
  bin_items<<<nbBin, 256, 0, stream>>>(ei, nE, total, nbkt, gfront, binned);
  bucket_finalize<<<nbkt, BROW, 0, stream>>>(binned, bkt_off, row_ptr, dis, ev, nN, nbkt);

  const int gemm_grid = (nN + 63) / 64;
  const int node_grid = (nN + 3) / 4;

  // layer 1
  gemm_mfma<false><<<gemm_grid, 256, 0, stream>>>(x, nullptr, Wt1, dis, hb, nN);
  aggregate<<<node_grid, 256, 0, stream>>>(hb, row_ptr, ev, dis, b1, hbA, 1, nN);
  // layer 2
  gemm_mfma<true><<<gemm_grid, 256, 0, stream>>>(nullptr, hbA, Wt2, dis, hb, nN);
  aggregate<<<node_grid, 256, 0, stream>>>(hb, row_ptr, ev, dis, b2, hbA, 1, nN);
  // layer 3 folded with classifier
  gemm_small<<<(nN + 255) / 256, 256, 0, stream>>>(hbA, Wf, dis, Gb, nN);
  agg_logits<<<node_grid, 256, 0, stream>>>(Gb, row_ptr, ev, dis, bfv, out, nN);
}